// Round 1
// baseline (1560.039 us; speedup 1.0000x reference)
//
#include <hip/hip_runtime.h>
#include <hip/hip_bf16.h>

// Problem constants (static per reference)
#define NUM_E   8
#define D_IN    4096
#define D_OUT   4096
#define TPE     2048
#define T_TOTAL (NUM_E * TPE)

// Tile config: 128x128 tile, BK=32, 256 threads (4 waves, 2x2), each wave 64x64
#define BM 128
#define BN 128
#define BK 32

typedef __bf16 bf16_8 __attribute__((ext_vector_type(8)));
typedef __bf16 bf16_4 __attribute__((ext_vector_type(4)));
typedef float  f32x4  __attribute__((ext_vector_type(4)));

// ---------------------------------------------------------------------------
// Pre-pass: one-shot fp32 -> bf16 conversion (each element converted ONCE,
// instead of 16-32x inside the GEMM K-loop). Memory-bound: ~1.15 GB traffic.
// ---------------------------------------------------------------------------
__global__ __launch_bounds__(256)
void cvt_f32_bf16(const float* __restrict__ src, __bf16* __restrict__ dst,
                  size_t n8)  // number of 8-element groups
{
    size_t i = (size_t)blockIdx.x * blockDim.x + threadIdx.x;
    const size_t stride = (size_t)gridDim.x * blockDim.x;
    for (; i < n8; i += stride) {
        const float4 a = *reinterpret_cast<const float4*>(src + i * 8);
        const float4 b = *reinterpret_cast<const float4*>(src + i * 8 + 4);
        bf16_8 v;
        v[0] = (__bf16)a.x; v[1] = (__bf16)a.y;
        v[2] = (__bf16)a.z; v[3] = (__bf16)a.w;
        v[4] = (__bf16)b.x; v[5] = (__bf16)b.y;
        v[6] = (__bf16)b.z; v[7] = (__bf16)b.w;
        *reinterpret_cast<bf16_8*>(dst + i * 8) = v;  // 16B store
    }
}

// ---------------------------------------------------------------------------
// Main GEMM (m97 structure): bf16 inputs, global_load_lds width=16 staging,
// linear [128][32] LDS, 16x16x32 MFMA, 4x4 acc per wave.
// Fragment/epilogue layout identical to the previously harness-verified kernel.
// ---------------------------------------------------------------------------
__device__ __forceinline__ void gload_lds16(const void* g, void* l)
{
    __builtin_amdgcn_global_load_lds(
        (const __attribute__((address_space(1))) void*)g,
        (__attribute__((address_space(3))) void*)l,
        16 /*bytes, literal*/, 0 /*offset*/, 0 /*aux*/);
}

__global__ __launch_bounds__(256, 3)
void gemm_bt_bf16(const __bf16* __restrict__ A,   // [T_TOTAL][D_IN] bf16
                  const __bf16* __restrict__ W,   // [E][D_OUT][D_IN] bf16
                  float* __restrict__ out)
{
    const int nTile = blockIdx.x;          // 0..31
    const int mTile = blockIdx.y;          // 0..127
    const int expert = mTile >> 4;         // 2048/128 = 16 m-tiles per expert
    const int rowStart = mTile * BM;
    const int colStart = nTile * BN;

    const __bf16* Abase = A + (size_t)rowStart * D_IN;
    const __bf16* Bbase = W + ((size_t)expert * D_OUT + colStart) * D_IN;

    // Linear row-major LDS: As[row][k] with BK=32 (64B rows).
    // global_load_lds requires the LDS dest to be linear in lane order — it is:
    // lane l of issue `it` writes As + (it*256 + wave*64 + l)*16 bytes.
    __shared__ __align__(16) __bf16 As[BM * BK];
    __shared__ __align__(16) __bf16 Bs[BN * BK];

    const int tid  = threadIdx.x;
    const int lane = tid & 63;
    const int wave = tid >> 6;             // 0..3
    const int wm   = (wave >> 1) * 64;     // wave's 64x64 sub-tile origin
    const int wn   = (wave & 1) * 64;

    const int kq = lane >> 4;              // k-quarter (which 8-wide k block)
    const int lr = lane & 15;              // row-within-16 for A/B fragments

    // Staging coordinates: idx in [0,512) covers 128 rows x 4 chunks of 8 bf16
    const int idx0 = tid;                  // rows 0..63
    const int idx1 = 256 + tid;            // rows 64..127
    const int r0 = idx0 >> 2, c0 = (idx0 & 3) * 8;
    const int r1 = idx1 >> 2, c1 = (idx1 & 3) * 8;

    f32x4 acc[4][4];
    #pragma unroll
    for (int i = 0; i < 4; ++i)
        #pragma unroll
        for (int j = 0; j < 4; ++j)
            acc[i][j] = (f32x4){0.f, 0.f, 0.f, 0.f};

    for (int k0 = 0; k0 < D_IN; k0 += BK) {
        __syncthreads();   // previous compute must finish reading LDS

        // Async global->LDS, 16B per lane, 4 issues/thread total (A:2, B:2).
        gload_lds16(Abase + (size_t)r0 * D_IN + k0 + c0, &As[idx0 * 8]);
        gload_lds16(Abase + (size_t)r1 * D_IN + k0 + c1, &As[idx1 * 8]);
        gload_lds16(Bbase + (size_t)r0 * D_IN + k0 + c0, &Bs[idx0 * 8]);
        gload_lds16(Bbase + (size_t)r1 * D_IN + k0 + c1, &Bs[idx1 * 8]);

        __syncthreads();   // compiler emits vmcnt(0) drain before s_barrier

        // Fragments: A[m=lane&15][k=kq*8+j], B[k=kq*8+j][n=lane&15] (=W[n][k])
        bf16_8 afrag[4], bfrag[4];
        #pragma unroll
        for (int mt = 0; mt < 4; ++mt)
            afrag[mt] = *reinterpret_cast<const bf16_8*>(
                &As[(wm + mt * 16 + lr) * BK + kq * 8]);
        #pragma unroll
        for (int nt = 0; nt < 4; ++nt)
            bfrag[nt] = *reinterpret_cast<const bf16_8*>(
                &Bs[(wn + nt * 16 + lr) * BK + kq * 8]);

        #pragma unroll
        for (int mt = 0; mt < 4; ++mt)
            #pragma unroll
            for (int nt = 0; nt < 4; ++nt)
                acc[mt][nt] = __builtin_amdgcn_mfma_f32_16x16x32_bf16(
                    afrag[mt], bfrag[nt], acc[mt][nt], 0, 0, 0);
    }

    // Epilogue: C/D layout col=lane&15, row=(lane>>4)*4+r (m89/m91-verified)
    const int cn = lane & 15;
    const int cr = (lane >> 4) * 4;
    #pragma unroll
    for (int mt = 0; mt < 4; ++mt) {
        #pragma unroll
        for (int nt = 0; nt < 4; ++nt) {
            #pragma unroll
            for (int r = 0; r < 4; ++r) {
                const int m = wm + mt * 16 + cr + r;
                const int n = wn + nt * 16 + cn;
                out[(size_t)(rowStart + m) * D_OUT + colStart + n] = acc[mt][nt][r];
            }
        }
    }
}

// ---------------------------------------------------------------------------
// Fallback: the previously harness-verified fused-conversion kernel (1689.6us),
// used only if the workspace is too small for the bf16 copies.
// ---------------------------------------------------------------------------
__global__ __launch_bounds__(256, 2)
void grouped_gemm_fallback(const float* __restrict__ inp,
                           const float* __restrict__ wgt,
                           float* __restrict__ out)
{
    const int nTile = blockIdx.x;
    const int mTile = blockIdx.y;
    const int expert = mTile >> 4;
    const int rowStart = mTile * BM;
    const int colStart = nTile * BN;

    const float* Abase = inp + (size_t)rowStart * D_IN;
    const float* Bbase = wgt + (size_t)expert * D_OUT * D_IN + (size_t)colStart * D_IN;

    __shared__ __bf16 As[4][BM][8];
    __shared__ __bf16 Bs[4][BN][8];

    const int tid  = threadIdx.x;
    const int lane = tid & 63;
    const int wave = tid >> 6;
    const int wm   = (wave >> 1) * 64;
    const int wn   = (wave & 1) * 64;

    const int kq = lane >> 4;
    const int lr = lane & 15;

    f32x4 acc[4][4];
    #pragma unroll
    for (int i = 0; i < 4; ++i)
        #pragma unroll
        for (int j = 0; j < 4; ++j)
            acc[i][j] = (f32x4){0.f, 0.f, 0.f, 0.f};

    for (int k0 = 0; k0 < D_IN; k0 += BK) {
        __syncthreads();
        #pragma unroll
        for (int it = 0; it < 4; ++it) {
            const int idx = (it * 256 + tid) * 4;
            const int row = idx >> 5;
            const int col = idx & 31;
            const float4 av = *reinterpret_cast<const float4*>(
                Abase + (size_t)row * D_IN + k0 + col);
            const float4 bv = *reinterpret_cast<const float4*>(
                Bbase + (size_t)row * D_IN + k0 + col);
            bf16_4 a4, b4;
            a4.x = (__bf16)av.x; a4.y = (__bf16)av.y;
            a4.z = (__bf16)av.z; a4.w = (__bf16)av.w;
            b4.x = (__bf16)bv.x; b4.y = (__bf16)bv.y;
            b4.z = (__bf16)bv.z; b4.w = (__bf16)bv.w;
            *reinterpret_cast<bf16_4*>(&As[col >> 3][row][col & 7]) = a4;
            *reinterpret_cast<bf16_4*>(&Bs[col >> 3][row][col & 7]) = b4;
        }
        __syncthreads();

        bf16_8 afrag[4], bfrag[4];
        #pragma unroll
        for (int mt = 0; mt < 4; ++mt)
            afrag[mt] = *reinterpret_cast<const bf16_8*>(&As[kq][wm + mt * 16 + lr][0]);
        #pragma unroll
        for (int nt = 0; nt < 4; ++nt)
            bfrag[nt] = *reinterpret_cast<const bf16_8*>(&Bs[kq][wn + nt * 16 + lr][0]);

        #pragma unroll
        for (int mt = 0; mt < 4; ++mt)
            #pragma unroll
            for (int nt = 0; nt < 4; ++nt)
                acc[mt][nt] = __builtin_amdgcn_mfma_f32_16x16x32_bf16(
                    afrag[mt], bfrag[nt], acc[mt][nt], 0, 0, 0);
    }

    const int cn = lane & 15;
    const int cr = (lane >> 4) * 4;
    #pragma unroll
    for (int mt = 0; mt < 4; ++mt) {
        #pragma unroll
        for (int nt = 0; nt < 4; ++nt) {
            #pragma unroll
            for (int r = 0; r < 4; ++r) {
                const int m = wm + mt * 16 + cr + r;
                const int n = wn + nt * 16 + cn;
                out[(size_t)(rowStart + m) * D_OUT + colStart + n] = acc[mt][nt][r];
            }
        }
    }
}

// ---------------------------------------------------------------------------
extern "C" void kernel_launch(void* const* d_in, const int* in_sizes, int n_in,
                              void* d_out, int out_size, void* d_ws, size_t ws_size,
                              hipStream_t stream) {
    const float* inp = (const float*)d_in[0];   // [T_TOTAL, D_IN] fp32
    const float* wgt = (const float*)d_in[1];   // [E, D_OUT, D_IN] fp32
    // d_in[2] = num_tokens_per_expert: static 2048 each (reference reshapes
    // assuming equal counts), hardcoded in the kernel's expert indexing.
    float* out = (float*)d_out;                 // [T_TOTAL, D_OUT] fp32

    const size_t WGT_E = (size_t)NUM_E * D_OUT * D_IN;   // 134,217,728 elems
    const size_t INP_E = (size_t)T_TOTAL * D_IN;         //  67,108,864 elems
    const size_t need  = (WGT_E + INP_E) * sizeof(__bf16); // 384 MiB

    dim3 grid(D_OUT / BN, T_TOTAL / BM);        // 32 x 128 = 4096 blocks

    if (d_ws != nullptr && ws_size >= need) {
        __bf16* wgt_bf = (__bf16*)d_ws;
        __bf16* inp_bf = wgt_bf + WGT_E;        // offset 256 MiB, aligned
        cvt_f32_bf16<<<2048, 256, 0, stream>>>(wgt, wgt_bf, WGT_E / 8);
        cvt_f32_bf16<<<2048, 256, 0, stream>>>(inp, inp_bf, INP_E / 8);
        gemm_bt_bf16<<<grid, 256, 0, stream>>>(inp_bf, wgt_bf, out);
    } else {
        grouped_gemm_fallback<<<grid, 256, 0, stream>>>(inp, wgt, out);
    }
}